// Round 4
// baseline (497.743 us; speedup 1.0000x reference)
//
#include <hip/hip_runtime.h>

// GraphConvGRU: B=16384, IN=32, HID=3, N=22 nodes, T=100 steps.
// Graph collapses to 3 node-equivalence classes -> per-chain state is 9 floats,
// 22x22 normalized adjacency reduces exactly to 3x3 (verified; R0-R2 passed,
// absmax 3.9e-3).
//
// R3 change: barrier-free streaming stores.
//   R2's per-chunk __syncthreads compiled to s_waitcnt vmcnt(0) before
//   s_barrier -> every chunk drained ALL outstanding global stores before
//   computing (25 synchronous drains). With TPB=64 the block is ONE wave:
//   per-wave DS ordering + compiler lgkmcnt tracking make barriers
//   unnecessary. Removed entirely; stores now stream, overlapped with the
//   next chunk's compute. SCH 4->10 (single LDS buffer, 23.3KB, 4 blk/CU)
//   lengthens store runs to 2640B (fewer partial-line RMWs) and cuts
//   per-chunk overhead count.

#define TPB 64
#define REP 4
#define RPW 16                      // rows stored per replica = TPB/REP
#define NGRP (16384 / TPB)          // 256 chain-groups
#define GRID (NGRP * REP)           // 1024 blocks
#define T_TOTAL 100
#define SCH 10                      // steps per chunk
#define NCHUNK (T_TOTAL / SCH)      // 10
#define ROW_F4 (SCH * 66 / 4)       // 165 float4 per (row, chunk)
#define STG_STRIDE (SCH * 9 + 1)    // 91 floats per thread-row (odd: bank spread)
#define STG_SZ (TPB * STG_STRIDE)   // 5824 floats (23.3 KB, single buffer)
#define F4_PER_REP (RPW * ROW_F4)   // 2640 f4 per replica per chunk
#define GITERS ((F4_PER_REP + TPB - 1) / TPB)   // 42

#if __has_builtin(__builtin_amdgcn_exp2f)
#define EXP2F __builtin_amdgcn_exp2f
#else
#define EXP2F exp2f
#endif
#if __has_builtin(__builtin_amdgcn_rcpf)
#define RCPF __builtin_amdgcn_rcpf
#else
#define RCPF(x) (1.0f / (x))
#endif

static __device__ __forceinline__ float fast_sigmoid(float x) {
    float e = EXP2F(-1.44269504f * x);
    return RCPF(1.0f + e);
}
static __device__ __forceinline__ float fast_tanh(float x) {
    float e = EXP2F(2.88539008f * x);          // exp(2x)
    return 1.0f - 2.0f * RCPF(1.0f + e);
}

__global__ __launch_bounds__(TPB) void gcgru_kernel(
    const float* __restrict__ x,
    const float* __restrict__ w_r_W, const float* __restrict__ w_r_b,
    const float* __restrict__ w_z_W, const float* __restrict__ w_z_b,
    const float* __restrict__ w_h_W, const float* __restrict__ w_h_b,
    const float* __restrict__ gcn_W, const float* __restrict__ gcn_b,
    float* __restrict__ out)
{
    __shared__ float wS[297];           // w_r_W[96], w_z_W[96], w_h_W[96], biases r/z/h [9]
    __shared__ float gwS[9];
    __shared__ float gbS[3];
    __shared__ unsigned int tabS[ROW_F4];   // per-f4 packed state-index table
    __shared__ float stage[STG_SZ];         // single-buffer compact states (1 wave)

    const int tid = threadIdx.x;            // 0..63, chain within group
    const int rep = blockIdx.x & (REP - 1); // replica id 0..3
    const int b0  = (blockIdx.x >> 2) * TPB;
    const int row0 = rep * RPW;             // first row this replica stores

    // ---- one-time: stage weights + build expansion table (same wave: no barrier) ----
    for (int i = tid; i < 96; i += TPB) {
        wS[i]       = w_r_W[i];
        wS[96 + i]  = w_z_W[i];
        wS[192 + i] = w_h_W[i];
    }
    if (tid < 3) {
        wS[288 + tid] = w_r_b[tid];
        wS[291 + tid] = w_z_b[tid];
        wS[294 + tid] = w_h_b[tid];
        gbS[tid] = gcn_b[tid];
    }
    if (tid < 9) gwS[tid] = gcn_W[tid];
    {
        // cls3[k] = class(node k/3)*3 + k%3 for k in [0,66)
        static const unsigned char cls3[66] = {
            0,1,2, 3,4,5, 3,4,5, 6,7,8, 3,4,5, 3,4,5, 6,7,8, 3,4,5, 3,4,5,
            0,1,2, 3,4,5, 3,4,5, 6,7,8, 3,4,5, 3,4,5, 6,7,8, 3,4,5, 3,4,5,
            3,4,5, 3,4,5, 3,4,5, 3,4,5
        };
        for (int j4 = tid; j4 < ROW_F4; j4 += TPB) {
            unsigned int w = 0;
            #pragma unroll
            for (int u = 0; u < 4; ++u) {
                int jj = 4 * j4 + u;         // 0..SCH*66-1 within a chunk-row
                int tl = jj / 66;            // local step 0..SCH-1
                int k  = jj - 66 * tl;       // 0..65
                w |= (unsigned int)(tl * 9 + cls3[k]) << (8 * u);
            }
            tabS[j4] = w;
        }
    }

    // ---- per-chain input projections: xr/xz/xh = x @ W + b ----
    float xv[32];
    {
        const float4* xp = reinterpret_cast<const float4*>(x + (size_t)(b0 + tid) * 32);
        #pragma unroll
        for (int i = 0; i < 8; ++i) {
            float4 v = xp[i];
            xv[4*i+0] = v.x; xv[4*i+1] = v.y; xv[4*i+2] = v.z; xv[4*i+3] = v.w;
        }
    }
    float xr[3], xz[3], xh[3];
    #pragma unroll
    for (int j = 0; j < 3; ++j) { xr[j] = wS[288+j]; xz[j] = wS[291+j]; xh[j] = wS[294+j]; }
    #pragma unroll
    for (int i = 0; i < 32; ++i) {
        float xi = xv[i];
        #pragma unroll
        for (int j = 0; j < 3; ++j) {
            xr[j] = fmaf(xi, wS[i*3+j],       xr[j]);
            xz[j] = fmaf(xi, wS[96 + i*3+j],  xz[j]);
            xh[j] = fmaf(xi, wS[192 + i*3+j], xh[j]);
        }
    }

    float W9[9], gb3[3];
    #pragma unroll
    for (int i = 0; i < 9; ++i) W9[i] = gwS[i];
    #pragma unroll
    for (int j = 0; j < 3; ++j) gb3[j] = gbS[j];

    // reduced symmetric-normalized adjacency (3 classes), exact:
    const float M00 = 0.0769230769f;   // 1/13
    const float M01 = 1.1094003925f;   // 4/sqrt(13)
    const float M02 = 0.4961389384f;   // 4/sqrt(65)
    const float M10 = 0.1386750491f;   // 1/(2 sqrt(13))
    const float M11 = 0.75f;
    const float M20 = 0.2480694691f;   // 2/sqrt(65)
    const float M22 = 0.6f;

    float h[9];
    #pragma unroll
    for (int i = 0; i < 9; ++i) h[i] = 0.0f;

    float4* out4 = reinterpret_cast<float4*>(out);

    for (int chunk = 0; chunk < NCHUNK; ++chunk) {
        float* stw = stage + tid * STG_STRIDE;

        #pragma unroll
        for (int s = 0; s < SCH; ++s) {
            float mh[9], gh[9];
            #pragma unroll
            for (int j = 0; j < 3; ++j) {
                mh[j]     = M00 * h[j] + M01 * h[3+j] + M02 * h[6+j];
                mh[3 + j] = M10 * h[j] + M11 * h[3+j];
                mh[6 + j] = M20 * h[j] + M22 * h[6+j];
            }
            #pragma unroll
            for (int c = 0; c < 3; ++c)
                #pragma unroll
                for (int j = 0; j < 3; ++j)
                    gh[c*3+j] = gb3[j] + mh[c*3+0]*W9[j] + mh[c*3+1]*W9[3+j] + mh[c*3+2]*W9[6+j];
            #pragma unroll
            for (int c = 0; c < 3; ++c) {
                #pragma unroll
                for (int j = 0; j < 3; ++j) {
                    float g  = gh[c*3+j];
                    float r  = fast_sigmoid(xr[j] + g);
                    float z  = fast_sigmoid(xz[j] + g);
                    float ht = fast_tanh(xh[j] + r * g);
                    float hv = h[c*3+j];
                    h[c*3+j] = hv + z * (ht - hv);
                }
            }
            #pragma unroll
            for (int q = 0; q < 9; ++q) stw[s*9 + q] = h[q];
        }

        // NO barrier: single-wave block; DS pipe is in-order per wave and the
        // compiler orders aliasing LDS write->read with lgkmcnt. Global stores
        // from previous chunks keep streaming (no vmcnt(0) drain).

        // contiguous-ownership expansion: this replica writes rows
        // [row0, row0+16) of the group; 2640B runs per row per chunk.
        const int cbase = chunk * ROW_F4;
        for (int i = 0; i < GITERS; ++i) {
            int f = i * TPB + tid;           // 0..F4_PER_REP-1 within replica span
            if (f < F4_PER_REP) {
                int rl = f / ROW_F4;         // 0..15
                int j4 = f - rl * ROW_F4;    // 0..164
                int r  = row0 + rl;
                unsigned int tw = tabS[j4];
                const float* row = stage + r * STG_STRIDE;
                float4 v;
                v.x = row[tw & 255u];
                v.y = row[(tw >> 8)  & 255u];
                v.z = row[(tw >> 16) & 255u];
                v.w = row[tw >> 24];
                out4[(size_t)(b0 + r) * 1650 + cbase + j4] = v;
            }
        }
    }
}

extern "C" void kernel_launch(void* const* d_in, const int* in_sizes, int n_in,
                              void* d_out, int out_size, void* d_ws, size_t ws_size,
                              hipStream_t stream) {
    const float* xp     = (const float*)d_in[0];
    const float* w_r_W  = (const float*)d_in[1];
    const float* w_r_b  = (const float*)d_in[2];
    const float* w_z_W  = (const float*)d_in[3];
    const float* w_z_b  = (const float*)d_in[4];
    const float* w_h_W  = (const float*)d_in[5];
    const float* w_h_b  = (const float*)d_in[6];
    const float* gcn_W  = (const float*)d_in[7];
    const float* gcn_b  = (const float*)d_in[8];
    float* outp = (float*)d_out;

    gcgru_kernel<<<GRID, TPB, 0, stream>>>(xp, w_r_W, w_r_b, w_z_W, w_z_b,
                                           w_h_W, w_h_b, gcn_W, gcn_b, outp);
}